// Round 7
// baseline (9340.596 us; speedup 1.0000x reference)
//
#include <hip/hip_runtime.h>

// ---------------------------------------------------------------------------
// SpikeRNN — r7: exact numpy-f32 emulation, f32 output (bf16 theory RETRACTED:
// r5's 1.914 = 1.0-(-0.914) proves f32 readback; r1-r4's 0.691 < max|ref| is
// a correlated, late-divergence signature -> marginal spike flips vs np's f32
// chains). Emulation:
//   in_ff  : np.einsum naive = serial c-ascending f32 mul+add, NO FMA
//   rec/h2 : sgemm k-chain == plain f32 adds of spiking weights, ascending i
//   state  : separate-ufunc f32 ops, reference order, no contraction
// ---------------------------------------------------------------------------

constexpr int NB_IN  = 256;
constexpr int NB_REC = 1024;
constexpr int NB_OUT = 64;
constexpr int BATCH  = 128;
constexpr int NB_STEPS = 300;
constexpr int TSTEPS = NB_STEPS - 1;

constexpr float ALPHA_F = (float)0.8187307530779818;  // f32(exp(-0.2))
constexpr float BETA_F  = (float)0.9048374180359595;  // f32(exp(-0.1))

// d_out element offsets (f32 elements)
constexpr size_t OUT_REC_OFF = 0;
constexpr size_t SPK_REC_OFF = (size_t)BATCH * NB_STEPS * NB_OUT;
constexpr size_t WRECD_OFF   = SPK_REC_OFF + (size_t)BATCH * NB_STEPS * NB_REC;
constexpr size_t WOUTD_OFF   = WRECD_OFF + (size_t)NB_REC * NB_REC;
constexpr size_t WFF_OFF     = WOUTD_OFF + (size_t)NB_REC * NB_OUT;
constexpr int    OUT_TOTAL   = 43155456;

constexpr int SZ_INPUTS = BATCH * NB_STEPS * NB_IN;   // 9,830,400
constexpr int SZ_NOISE  = BATCH * NB_STEPS * NB_REC;  // 39,321,600
constexpr int SZ_WFF    = NB_IN * NB_REC;             // 262,144
constexpr int SZ_WREC   = NB_REC * NB_REC;            // 1,048,576
constexpr int SZ_WOUT   = NB_REC * NB_OUT;            // 65,536
constexpr int SZ_DSIGN  = NB_REC;                     // 1,024

__global__ void sentinel_kernel(float* out, float v) { out[0] = v; }

// ---------------------------------------------------------------------------
// Dale weights (exact f32 sign*abs): f32 into d_ws for the sim, f32 into
// d_out for scoring; w_ff passthrough.
// ---------------------------------------------------------------------------
__global__ void weights_kernel(const float* __restrict__ w_rec,
                               const float* __restrict__ w_out,
                               const float* __restrict__ w_ff,
                               const float* __restrict__ d_sign,
                               float* __restrict__ f_wrecd,
                               float* __restrict__ f_woutd,
                               float* __restrict__ o_wrecd,
                               float* __restrict__ o_woutd,
                               float* __restrict__ o_wff) {
  int idx = blockIdx.x * blockDim.x + threadIdx.x;
  if (idx < NB_REC * NB_REC) {
    int i = idx >> 10;
    float v = d_sign[i] * fabsf(w_rec[idx]);
    f_wrecd[idx] = v;
    o_wrecd[idx] = v;
    return;
  }
  int idx2 = idx - NB_REC * NB_REC;
  if (idx2 < NB_REC * NB_OUT) {
    int i = idx2 >> 6;
    float v = d_sign[i] * fabsf(w_out[idx2]);
    f_woutd[idx2] = v;
    o_woutd[idx2] = v;
    return;
  }
  int idx3 = idx2 - NB_REC * NB_OUT;
  if (idx3 < NB_IN * NB_REC) {
    o_wff[idx3] = w_ff[idx3];
  }
}

// ---------------------------------------------------------------------------
// in_ff = inputs @ w_ff emulating np.einsum (optimize=False): per element,
// serial c = 0..255, f32 single accumulator, separate mul and add roundings.
// Block: 8 rows x 256 cols of d; w value reused across the 8 rows.
// ---------------------------------------------------------------------------
__global__ __launch_bounds__(256)
void inff_einsum(const float* __restrict__ A,    // [rows,256]
                 const float* __restrict__ Bw,   // [256,1024]
                 float* __restrict__ C,          // [rows,1024]
                 int rows) {
  const int r0 = blockIdx.x * 8;
  const int d  = blockIdx.y * 256 + threadIdx.x;

  __shared__ float a_s[8][NB_IN];
  for (int e = threadIdx.x; e < 8 * NB_IN; e += 256) {
    int rr = e >> 8, cc = e & 255;
    a_s[rr][cc] = (r0 + rr < rows) ? A[(size_t)(r0 + rr) * NB_IN + cc] : 0.0f;
  }
  __syncthreads();

  float acc[8] = {0.f, 0.f, 0.f, 0.f, 0.f, 0.f, 0.f, 0.f};
  for (int c = 0; c < NB_IN; ++c) {
    const float w = Bw[(size_t)c * NB_REC + d];
#pragma unroll
    for (int rr = 0; rr < 8; ++rr)
      acc[rr] = __fadd_rn(acc[rr], __fmul_rn(a_s[rr][c], w));  // no FMA
  }
#pragma unroll
  for (int rr = 0; rr < 8; ++rr)
    if (r0 + rr < rows) C[(size_t)(r0 + rr) * NB_REC + d] = acc[rr];
}

// ---------------------------------------------------------------------------
// 299-step recurrence. 1 block/batch element, thread j = neuron j.
// Spike set as a 32-word LDS bitmask (deterministic ASCENDING-i iteration —
// required: sgemm's k-chain order). rec/h2 = serial f32 adds of spiking
// weights (bit-equal to sgemm's fma(1,w,acc) chain; zero terms are no-ops).
// f32 state, reference op order, no contraction. f32 outputs.
// ---------------------------------------------------------------------------
__global__ __launch_bounds__(1024, 1)
void rnn_kernel(const float* __restrict__ inff,    // [cb,300,1024]
                const float* __restrict__ noise,   // (pre-offset)
                const float* __restrict__ w_rec_d, // f32, ws
                const float* __restrict__ w_out_d, // f32, ws
                float* __restrict__ out_rec,       // (pre-offset)
                float* __restrict__ spk_rec) {     // (pre-offset)
  const int b = blockIdx.x;
  const int j = threadIdx.x;
  const int lane = j & 63;
  const int wv = j >> 6;       // wave index 0..15

  __shared__ unsigned s_mask[32];

  float syn = 0.0f, mem = 0.0f;
  int rst1 = 0, rst2 = 0;

  spk_rec[((size_t)b * NB_STEPS) * NB_REC + j] = 0.0f;
  if (j < NB_OUT) out_rec[((size_t)b * NB_STEPS) * NB_OUT + j] = 0.0f;

  const float* wc = w_rec_d + j;   // column j, row stride 1024
  const float* wo = w_out_d + j;   // column j, row stride 64 (j<64 only)

  for (int t = 0; t < TSTEPS; ++t) {
    const float mem_eff = (rst1 | rst2) ? 0.0f : mem;
    const int spike = (__fsub_rn(mem_eff, 1.0f) > 0.0f) ? 1 : 0;

    const size_t row = (size_t)b * NB_STEPS + t;
    const float inf = inff[row * NB_REC + j];
    const float nz  = noise[row * NB_REC + j];

    unsigned long long msk = __ballot(spike);
    if (lane == 0) {
      s_mask[2 * wv]     = (unsigned)msk;
      s_mask[2 * wv + 1] = (unsigned)(msk >> 32);
    }
    __syncthreads();  // (1) bitmask complete

    // rec[j]: f32 adds of w_rec_d[i,j] over spiking i, ascending i
    float recf = 0.0f;
    for (int ww = 0; ww < 32; ++ww) {
      unsigned m = s_mask[ww];        // uniform across the block
      while (m) {
        const int bit = __builtin_ctz(m);
        m &= m - 1;
        recf = __fadd_rn(recf, wc[(size_t)(ww * 32 + bit) << 10]);
      }
    }

    // h2: same chain over w_out_d column j (threads j<64)
    if (j < NB_OUT) {
      float h2 = 0.0f;
      for (int ww = 0; ww < 32; ++ww) {
        unsigned m = s_mask[ww];
        while (m) {
          const int bit = __builtin_ctz(m);
          m &= m - 1;
          h2 = __fadd_rn(h2, wo[(size_t)(ww * 32 + bit) << 6]);
        }
      }
      out_rec[(row + 1) * NB_OUT + j] = h2;
    }

    // reference order, separate roundings, no FMA:
    const float new_syn =
        __fadd_rn(__fadd_rn(__fadd_rn(__fmul_rn(ALPHA_F, syn), recf), inf), nz);
    const float new_mem =
        __fsub_rn(__fadd_rn(__fmul_rn(BETA_F, mem_eff), syn), (float)spike);

    spk_rec[(row + 1) * NB_REC + j] = (float)spike;

    syn = new_syn;
    mem = new_mem;
    rst2 = rst1;
    rst1 = spike;

    __syncthreads();  // (2) s_mask reads done; next iter may rewrite
  }
}

// ---------------------------------------------------------------------------
extern "C" void kernel_launch(void* const* d_in, const int* in_sizes, int n_in,
                              void* d_out, int out_size, void* d_ws, size_t ws_size,
                              hipStream_t stream) {
  const float *inputs = nullptr, *noise = nullptr, *w_ff = nullptr,
              *w_rec = nullptr, *w_out = nullptr, *d_sign = nullptr;
  for (int i = 0; i < n_in; ++i) {
    switch (in_sizes[i]) {
      case SZ_INPUTS: inputs = (const float*)d_in[i]; break;
      case SZ_NOISE:  noise  = (const float*)d_in[i]; break;
      case SZ_WFF:    w_ff   = (const float*)d_in[i]; break;
      case SZ_WREC:   w_rec  = (const float*)d_in[i]; break;
      case SZ_WOUT:   w_out  = (const float*)d_in[i]; break;
      case SZ_DSIGN:  d_sign = (const float*)d_in[i]; break;
      default: break;
    }
  }

  float* out = (float*)d_out;
  const size_t W_BYTES = (size_t)(SZ_WREC + SZ_WOUT) * sizeof(float);

  float sentinel = 0.0f;
  if (!inputs || !noise || !w_ff || !w_rec || !w_out || !d_sign) {
    sentinel = 300.0f;
  } else if (out_size != OUT_TOTAL) {
    sentinel = 700.0f;
  }

  int CB = 0;
  if (sentinel == 0.0f) {
    const int cands[4] = {128, 64, 32, 16};
    for (int i = 0; i < 4; ++i) {
      size_t need = W_BYTES + (size_t)cands[i] * NB_STEPS * NB_REC * sizeof(float);
      if (need <= ws_size) { CB = cands[i]; break; }
    }
    if (CB == 0) sentinel = 500.0f + (float)(ws_size >> 20);
  }

  if (sentinel != 0.0f) {
    sentinel_kernel<<<1, 1, 0, stream>>>(out, sentinel);
    return;
  }

  float* out_rec = out + OUT_REC_OFF;
  float* spk_rec = out + SPK_REC_OFF;
  float* o_wrecd = out + WRECD_OFF;
  float* o_woutd = out + WOUTD_OFF;
  float* o_wff   = out + WFF_OFF;

  float* f_wrecd = (float*)d_ws;
  float* f_woutd = f_wrecd + SZ_WREC;
  float* inff    = f_woutd + SZ_WOUT;

  {
    int total = NB_REC * NB_REC + NB_REC * NB_OUT + NB_IN * NB_REC;
    int blocks = (total + 255) / 256;
    weights_kernel<<<blocks, 256, 0, stream>>>(w_rec, w_out, w_ff, d_sign,
                                               f_wrecd, f_woutd,
                                               o_wrecd, o_woutd, o_wff);
  }

  for (int b0 = 0; b0 < BATCH; b0 += CB) {
    const int cb = (BATCH - b0 < CB) ? (BATCH - b0) : CB;
    const int rows = cb * NB_STEPS;
    const float* Aptr = inputs + (size_t)b0 * NB_STEPS * NB_IN;
    const float* Nptr = noise + (size_t)b0 * NB_STEPS * NB_REC;
    float* orec = out_rec + (size_t)b0 * NB_STEPS * NB_OUT;
    float* srec = spk_rec + (size_t)b0 * NB_STEPS * NB_REC;

    dim3 ggrid((rows + 7) / 8, NB_REC / 256);
    inff_einsum<<<ggrid, 256, 0, stream>>>(Aptr, w_ff, inff, rows);
    rnn_kernel<<<cb, NB_REC, 0, stream>>>(inff, Nptr, f_wrecd, f_woutd,
                                          orec, srec);
  }
}

// Round 8
// 3134.059 us; speedup vs baseline: 2.9804x; 2.9804x over previous
//
#include <hip/hip_runtime.h>

// ---------------------------------------------------------------------------
// SpikeRNN — r8: same exact-numpy-f32 numerics as the passing r7, optimized.
//  * rnn_kernel: deterministic wave0 compaction (ascending sidx) + grouped,
//    double-buffered weight loads (8 independent loads in flight per group);
//    the f32 add chain itself stays strictly serial ascending (bit-exact).
//  * h2/out_rec moved to a separate massively-parallel kernel (38400 rows).
//  * einsum unchanged (near its no-FMA VALU floor).
// ---------------------------------------------------------------------------

constexpr int NB_IN  = 256;
constexpr int NB_REC = 1024;
constexpr int NB_OUT = 64;
constexpr int BATCH  = 128;
constexpr int NB_STEPS = 300;
constexpr int TSTEPS = NB_STEPS - 1;

constexpr float ALPHA_F = (float)0.8187307530779818;  // f32(exp(-0.2))
constexpr float BETA_F  = (float)0.9048374180359595;  // f32(exp(-0.1))

// d_out element offsets (f32 elements)
constexpr size_t OUT_REC_OFF = 0;
constexpr size_t SPK_REC_OFF = (size_t)BATCH * NB_STEPS * NB_OUT;
constexpr size_t WRECD_OFF   = SPK_REC_OFF + (size_t)BATCH * NB_STEPS * NB_REC;
constexpr size_t WOUTD_OFF   = WRECD_OFF + (size_t)NB_REC * NB_REC;
constexpr size_t WFF_OFF     = WOUTD_OFF + (size_t)NB_REC * NB_OUT;
constexpr int    OUT_TOTAL   = 43155456;

constexpr int SZ_INPUTS = BATCH * NB_STEPS * NB_IN;   // 9,830,400
constexpr int SZ_NOISE  = BATCH * NB_STEPS * NB_REC;  // 39,321,600
constexpr int SZ_WFF    = NB_IN * NB_REC;             // 262,144
constexpr int SZ_WREC   = NB_REC * NB_REC;            // 1,048,576
constexpr int SZ_WOUT   = NB_REC * NB_OUT;            // 65,536
constexpr int SZ_DSIGN  = NB_REC;                     // 1,024

__global__ void sentinel_kernel(float* out, float v) { out[0] = v; }

// ---------------------------------------------------------------------------
// Dale weights (exact f32 sign*abs): f32 into d_ws for the sim + d_out copy.
// ---------------------------------------------------------------------------
__global__ void weights_kernel(const float* __restrict__ w_rec,
                               const float* __restrict__ w_out,
                               const float* __restrict__ w_ff,
                               const float* __restrict__ d_sign,
                               float* __restrict__ f_wrecd,
                               float* __restrict__ f_woutd,
                               float* __restrict__ o_wrecd,
                               float* __restrict__ o_woutd,
                               float* __restrict__ o_wff) {
  int idx = blockIdx.x * blockDim.x + threadIdx.x;
  if (idx < NB_REC * NB_REC) {
    int i = idx >> 10;
    float v = d_sign[i] * fabsf(w_rec[idx]);
    f_wrecd[idx] = v;
    o_wrecd[idx] = v;
    return;
  }
  int idx2 = idx - NB_REC * NB_REC;
  if (idx2 < NB_REC * NB_OUT) {
    int i = idx2 >> 6;
    float v = d_sign[i] * fabsf(w_out[idx2]);
    f_woutd[idx2] = v;
    o_woutd[idx2] = v;
    return;
  }
  int idx3 = idx2 - NB_REC * NB_OUT;
  if (idx3 < NB_IN * NB_REC) {
    o_wff[idx3] = w_ff[idx3];
  }
}

// ---------------------------------------------------------------------------
// in_ff = inputs @ w_ff emulating np.einsum: serial c-ascending f32 chain,
// separate mul/add roundings (no FMA). Unchanged from passing r7.
// ---------------------------------------------------------------------------
__global__ __launch_bounds__(256)
void inff_einsum(const float* __restrict__ A,    // [rows,256]
                 const float* __restrict__ Bw,   // [256,1024]
                 float* __restrict__ C,          // [rows,1024]
                 int rows) {
  const int r0 = blockIdx.x * 8;
  const int d  = blockIdx.y * 256 + threadIdx.x;

  __shared__ float a_s[8][NB_IN];
  for (int e = threadIdx.x; e < 8 * NB_IN; e += 256) {
    int rr = e >> 8, cc = e & 255;
    a_s[rr][cc] = (r0 + rr < rows) ? A[(size_t)(r0 + rr) * NB_IN + cc] : 0.0f;
  }
  __syncthreads();

  float acc[8] = {0.f, 0.f, 0.f, 0.f, 0.f, 0.f, 0.f, 0.f};
  for (int c = 0; c < NB_IN; ++c) {
    const float w = Bw[(size_t)c * NB_REC + d];
#pragma unroll
    for (int rr = 0; rr < 8; ++rr)
      acc[rr] = __fadd_rn(acc[rr], __fmul_rn(a_s[rr][c], w));  // no FMA
  }
#pragma unroll
  for (int rr = 0; rr < 8; ++rr)
    if (r0 + rr < rows) C[(size_t)(r0 + rr) * NB_REC + d] = acc[rr];
}

// ---------------------------------------------------------------------------
// 299-step recurrence. 1 block/batch element, thread j = neuron j.
// Per step: ballot -> mask words; wave0 builds ascending sidx via shfl-prefix;
// all threads gather column j with grouped (8) double-buffered loads.
// Add chain strictly serial ascending (pads add exact +0.0f). 2 barriers/step.
// ---------------------------------------------------------------------------
__global__ __launch_bounds__(1024, 1)
void rnn_kernel(const float* __restrict__ inff,    // [cb,300,1024]
                const float* __restrict__ noise,   // (pre-offset)
                const float* __restrict__ w_rec_d, // f32, ws
                float* __restrict__ spk_rec) {     // (pre-offset)
  const int b = blockIdx.x;
  const int j = threadIdx.x;
  const int lane = j & 63;
  const int wv = j >> 6;       // wave 0..15

  __shared__ unsigned s_mask[32];
  __shared__ uint4 sidx4_s[132];     // 1056 u16 (padded for group over-read)
  __shared__ int s_cnt;
  unsigned short* sidx = (unsigned short*)sidx4_s;
  const uint4* sidx4 = (const uint4*)sidx4_s;

  float syn = 0.0f, mem = 0.0f;
  int rst1 = 0, rst2 = 0;

  spk_rec[((size_t)b * NB_STEPS) * NB_REC + j] = 0.0f;

  const float* wc = w_rec_d + j;   // column j, row stride 1024 floats

  for (int t = 0; t < TSTEPS; ++t) {
    const float mem_eff = (rst1 | rst2) ? 0.0f : mem;
    const int spike = (__fsub_rn(mem_eff, 1.0f) > 0.0f) ? 1 : 0;

    const size_t row = (size_t)b * NB_STEPS + t;
    const float inf = inff[row * NB_REC + j];
    const float nz  = noise[row * NB_REC + j];

    const unsigned long long msk = __ballot(spike);
    if (lane == 0) {
      s_mask[2 * wv]     = (unsigned)msk;
      s_mask[2 * wv + 1] = (unsigned)(msk >> 32);
    }
    __syncthreads();  // (B1) mask words complete

    // wave 0: deterministic ascending compaction
    if (j < 32) {
      const unsigned m0 = s_mask[j];
      const int pc = __popc(m0);
      int x = pc;
#pragma unroll
      for (int d = 1; d < 32; d <<= 1) {
        int y = __shfl_up(x, (unsigned)d, 64);
        if (j >= d) x += y;
      }
      int base = x - pc;  // exclusive prefix
      unsigned m = m0;
      while (m) {
        sidx[base++] = (unsigned short)((j << 5) + __builtin_ctz(m));
        m &= m - 1;
      }
      if (j == 31) s_cnt = x;  // total spike count S
    }
    __syncthreads();  // (B2) sidx/s_cnt ready

    const int S = s_cnt;

    // grouped, double-buffered gather; serial ascending f32 add chain
    auto grp_load = [&](int k0, float* buf) {
      const uint4 pk = sidx4[k0 >> 3];
      const unsigned e[8] = {pk.x & 0xffffu, pk.x >> 16,
                             pk.y & 0xffffu, pk.y >> 16,
                             pk.z & 0xffffu, pk.z >> 16,
                             pk.w & 0xffffu, pk.w >> 16};
#pragma unroll
      for (int q = 0; q < 8; ++q) {
        const bool v = (k0 + q) < S;
        const float ld = wc[(size_t)(v ? e[q] : 0u) << 10];
        buf[q] = v ? ld : 0.0f;   // pad adds exact +0.0f
      }
    };

    float acc = 0.0f;
    float bufA[8], bufB[8];
    grp_load(0, bufA);
    for (int k0 = 0; k0 < S; k0 += 16) {
      grp_load(k0 + 8, bufB);
#pragma unroll
      for (int q = 0; q < 8; ++q) acc = __fadd_rn(acc, bufA[q]);
      grp_load(k0 + 16, bufA);
#pragma unroll
      for (int q = 0; q < 8; ++q) acc = __fadd_rn(acc, bufB[q]);
    }

    // reference order, separate roundings, no FMA
    const float new_syn =
        __fadd_rn(__fadd_rn(__fadd_rn(__fmul_rn(ALPHA_F, syn), acc), inf), nz);
    const float new_mem =
        __fsub_rn(__fadd_rn(__fmul_rn(BETA_F, mem_eff), syn), (float)spike);

    spk_rec[(row + 1) * NB_REC + j] = (float)spike;

    syn = new_syn;
    mem = new_mem;
    rst2 = rst1;
    rst1 = spike;
    // next iteration's B1 protects s_mask/sidx from premature overwrite
  }
}

// ---------------------------------------------------------------------------
// out_rec[r,:] = spk_rec[r,:] @ w_out_d for ALL 38400 rows (row 0 of each
// batch is all-zero -> writes 0). Same ascending serial f32 chain.
// 256 threads = 4 rows x 64 lanes; masks live in registers (ballot-uniform).
// ---------------------------------------------------------------------------
__global__ __launch_bounds__(256)
void h2_kernel(const float* __restrict__ spk_rec,  // [38400,1024]
               const float* __restrict__ w_out_d,  // [1024,64] f32, ws
               float* __restrict__ out_rec,        // [38400,64]
               int nrows) {
  const int r = blockIdx.x * 4 + (threadIdx.x >> 6);
  const int lane = threadIdx.x & 63;
  if (r >= nrows) return;

  const float* spk = spk_rec + (size_t)r * NB_REC;
  const float* wo  = w_out_d + lane;   // column `lane`, row stride 64

  unsigned long long mw[16];
#pragma unroll
  for (int c = 0; c < 16; ++c)
    mw[c] = __ballot(spk[c * 64 + lane] != 0.0f);

  float acc = 0.0f;
#pragma unroll
  for (int c = 0; c < 16; ++c) {
    unsigned long long m = mw[c];
    while (m) {                     // uniform across the wave
      float w[8];
#pragma unroll
      for (int q = 0; q < 8; ++q) {
        const bool v = (m != 0ull);
        const int idx = v ? __builtin_ctzll(m) : 0;
        m &= m - 1ull;
        const float ld = wo[(size_t)(v ? (c * 64 + idx) : 0) << 6];
        w[q] = v ? ld : 0.0f;
      }
#pragma unroll
      for (int q = 0; q < 8; ++q) acc = __fadd_rn(acc, w[q]);
    }
  }
  out_rec[(size_t)r * NB_OUT + lane] = acc;
}

// ---------------------------------------------------------------------------
extern "C" void kernel_launch(void* const* d_in, const int* in_sizes, int n_in,
                              void* d_out, int out_size, void* d_ws, size_t ws_size,
                              hipStream_t stream) {
  const float *inputs = nullptr, *noise = nullptr, *w_ff = nullptr,
              *w_rec = nullptr, *w_out = nullptr, *d_sign = nullptr;
  for (int i = 0; i < n_in; ++i) {
    switch (in_sizes[i]) {
      case SZ_INPUTS: inputs = (const float*)d_in[i]; break;
      case SZ_NOISE:  noise  = (const float*)d_in[i]; break;
      case SZ_WFF:    w_ff   = (const float*)d_in[i]; break;
      case SZ_WREC:   w_rec  = (const float*)d_in[i]; break;
      case SZ_WOUT:   w_out  = (const float*)d_in[i]; break;
      case SZ_DSIGN:  d_sign = (const float*)d_in[i]; break;
      default: break;
    }
  }

  float* out = (float*)d_out;
  const size_t W_BYTES = (size_t)(SZ_WREC + SZ_WOUT) * sizeof(float);

  float sentinel = 0.0f;
  if (!inputs || !noise || !w_ff || !w_rec || !w_out || !d_sign) {
    sentinel = 300.0f;
  } else if (out_size != OUT_TOTAL) {
    sentinel = 700.0f;
  }

  int CB = 0;
  if (sentinel == 0.0f) {
    const int cands[4] = {128, 64, 32, 16};
    for (int i = 0; i < 4; ++i) {
      size_t need = W_BYTES + (size_t)cands[i] * NB_STEPS * NB_REC * sizeof(float);
      if (need <= ws_size) { CB = cands[i]; break; }
    }
    if (CB == 0) sentinel = 500.0f + (float)(ws_size >> 20);
  }

  if (sentinel != 0.0f) {
    sentinel_kernel<<<1, 1, 0, stream>>>(out, sentinel);
    return;
  }

  float* out_rec = out + OUT_REC_OFF;
  float* spk_rec = out + SPK_REC_OFF;
  float* o_wrecd = out + WRECD_OFF;
  float* o_woutd = out + WOUTD_OFF;
  float* o_wff   = out + WFF_OFF;

  float* f_wrecd = (float*)d_ws;
  float* f_woutd = f_wrecd + SZ_WREC;
  float* inff    = f_woutd + SZ_WOUT;

  {
    int total = NB_REC * NB_REC + NB_REC * NB_OUT + NB_IN * NB_REC;
    int blocks = (total + 255) / 256;
    weights_kernel<<<blocks, 256, 0, stream>>>(w_rec, w_out, w_ff, d_sign,
                                               f_wrecd, f_woutd,
                                               o_wrecd, o_woutd, o_wff);
  }

  for (int b0 = 0; b0 < BATCH; b0 += CB) {
    const int cb = (BATCH - b0 < CB) ? (BATCH - b0) : CB;
    const int rows = cb * NB_STEPS;
    const float* Aptr = inputs + (size_t)b0 * NB_STEPS * NB_IN;
    const float* Nptr = noise + (size_t)b0 * NB_STEPS * NB_REC;
    float* srec = spk_rec + (size_t)b0 * NB_STEPS * NB_REC;

    dim3 ggrid((rows + 7) / 8, NB_REC / 256);
    inff_einsum<<<ggrid, 256, 0, stream>>>(Aptr, w_ff, inff, rows);
    rnn_kernel<<<cb, NB_REC, 0, stream>>>(inff, Nptr, f_wrecd, srec);
  }

  {
    const int nrows = BATCH * NB_STEPS;  // 38400
    h2_kernel<<<(nrows + 3) / 4, 256, 0, stream>>>(spk_rec, f_woutd,
                                                   out_rec, nrows);
  }
}